// Round 2
// baseline (201.596 us; speedup 1.0000x reference)
//
#include <hip/hip_runtime.h>

#define N_NODES 100000
#define N_EDGES 1600000
#define IN_CH 8
#define HID_CH 64
#define OUT_CH 2

// 1024 dst-ranges of 98 nodes (1024*98 = 100352 >= 100000).
#define R2   1024
#define RN   98
#define CAP  1920    // per-range capacity; Binom mean 1568, sd ~40 -> +8.9 sigma
#define BB   256     // bucket blocks
#define BCHUNK (N_EDGES / BB)   // 6250 edges per bucket block

// LDS accumulator strides (floats). 9 and 3 are coprime with 32 banks -> random
// dl values spread across all banks instead of aliasing to dl%4 / dl%16.
#define ACCS 9
#define A2S  3

// Native LDS float atomic add (ds_add_f32, fire-and-forget). Plain
// atomicAdd(float*) on LDS compiles to a CAS loop (denormal-safe path):
// 2-4 dependent ds round-trips per atomic -> the 88us sage1 of round 1.
// unsafeAtomicAdd lowers to the hardware instruction.
__device__ __forceinline__ void lds_fadd(float* p, float v) {
    unsafeAtomicAdd(p, v);
}

// ---- workspace (4-byte words), ~9.1 MB ----
//   cursor : R2        @ 0          (memset 0; per-range fill count)
//   bucket : R2*CAP    @ WS_BUCKET  (packed (dl<<17)|src; read by BOTH sage kernels)
//   deg    : R2*RN     @ WS_DEG     (in-degree per node)
//   g      : N*2 float @ WS_G       (W_l2 @ h per node)
#define WS_BUCKET 1024
#define WS_DEG    (WS_BUCKET + R2 * CAP)
#define WS_G      (WS_DEG + R2 * RN)

// Bin edges by dst-range: 2 LDS lane-atomics/edge + 1 global atomic per (block,range).
__global__ __launch_bounds__(512) void bucket_kernel(
        const int* __restrict__ src, const int* __restrict__ dst,
        int* __restrict__ cursor, int* __restrict__ bucket) {
    __shared__ int cnt[R2];
    __shared__ int base[R2];
    __shared__ int cur[R2];
    for (int i = threadIdx.x; i < R2; i += 512) { cnt[i] = 0; cur[i] = 0; }
    __syncthreads();
    const int* dch = dst + (size_t)blockIdx.x * BCHUNK;
    const int* sch = src + (size_t)blockIdx.x * BCHUNK;
    for (int j = threadIdx.x; j < BCHUNK; j += 512)
        atomicAdd(&cnt[(unsigned)dch[j] / RN], 1);
    __syncthreads();
    for (int i = threadIdx.x; i < R2; i += 512) {
        int c = cnt[i];
        base[i] = (c > 0) ? atomicAdd(&cursor[i], c) : 0;
    }
    __syncthreads();
    for (int j = threadIdx.x; j < BCHUNK; j += 512) {
        unsigned d = (unsigned)dch[j];
        unsigned r = d / RN;
        unsigned dl = d - r * RN;
        int slot = base[r] + atomicAdd(&cur[r], 1);
        if (slot < CAP)
            bucket[(size_t)r * CAP + slot] = (int)((dl << 17) | (unsigned)sch[j]);
    }
}

// Layer 1, one block per dst-range. NO sort, NO CSR: each edge is one
// independent iteration -> coalesced bucket read, L2-hot 32B gather of x[src],
// 8 native ds_add_f32 into acc[dl][*] + 1 int atomic for the degree.
__global__ __launch_bounds__(512) void sage1_range(
        const int* __restrict__ bucket, const int* __restrict__ cursor,
        const float* __restrict__ x,
        const float* __restrict__ W_l1, const float* __restrict__ b_l1,
        const float* __restrict__ W_r1,
        const float* __restrict__ W_l2, const float* __restrict__ b_l2,
        const float* __restrict__ W_r2,
        int* __restrict__ deg, float* __restrict__ g, float* __restrict__ out_rt) {
    __shared__ float acc[RN * ACCS];
    __shared__ int   cnt[RN];
    __shared__ float sWl[HID_CH * IN_CH];
    __shared__ float sWr[HID_CH * IN_CH];
    __shared__ float sb[HID_CH];
    __shared__ float sWl2[OUT_CH * HID_CH];
    __shared__ float sWr2[OUT_CH * HID_CH];
    __shared__ float sb2[OUT_CH];

    int tid = threadIdx.x;
    for (int i = tid; i < RN * ACCS; i += 512) acc[i] = 0.0f;
    if (tid < RN) cnt[tid] = 0;
    for (int i = tid; i < HID_CH * IN_CH; i += 512) {
        sWl[i] = W_l1[i];
        sWr[i] = W_r1[i];
    }
    for (int i = tid; i < HID_CH; i += 512) sb[i] = b_l1[i];
    for (int i = tid; i < OUT_CH * HID_CH; i += 512) {
        sWl2[i] = W_l2[i];
        sWr2[i] = W_r2[i];
    }
    if (tid < OUT_CH) sb2[tid] = b_l2[tid];
    __syncthreads();

    int r = blockIdx.x;
    int len = cursor[r];
    if (len > CAP) len = CAP;
    const int* bin = bucket + (size_t)r * CAP;
    for (int j = tid; j < len; j += 512) {
        int w = bin[j];
        int s = w & 0x1FFFF;
        int dl = w >> 17;
        const float4* xs = (const float4*)(x + (size_t)s * IN_CH);
        float4 a = xs[0];
        float4 b = xs[1];
        float* ap = acc + dl * ACCS;
        lds_fadd(ap + 0, a.x);
        lds_fadd(ap + 1, a.y);
        lds_fadd(ap + 2, a.z);
        lds_fadd(ap + 3, a.w);
        lds_fadd(ap + 4, b.x);
        lds_fadd(ap + 5, b.y);
        lds_fadd(ap + 6, b.z);
        lds_fadd(ap + 7, b.w);
        atomicAdd(&cnt[dl], 1);
    }
    __syncthreads();

    // MLP: 4 lanes per node, lane l handles hidden units [16l, 16l+16).
    int q = tid >> 2;
    int l = tid & 3;
    int node = r * RN + q;
    if (q < RN && node < N_NODES) {
        int dn = cnt[q];
        if (l == 0) deg[node] = dn;
        float inv = 1.0f / fmaxf((float)dn, 1.0f);
        float ag[IN_CH], xa[IN_CH];
        #pragma unroll
        for (int c = 0; c < IN_CH; c++) ag[c] = acc[q * ACCS + c] * inv;
        const float4* xp = (const float4*)(x + (size_t)node * IN_CH);
        float4 x0 = xp[0], x1 = xp[1];
        xa[0] = x0.x; xa[1] = x0.y; xa[2] = x0.z; xa[3] = x0.w;
        xa[4] = x1.x; xa[5] = x1.y; xa[6] = x1.z; xa[7] = x1.w;

        float g0 = 0.f, g1 = 0.f, r0 = 0.f, r1 = 0.f;
        int k0 = l * 16;
        #pragma unroll 4
        for (int kk = k0; kk < k0 + 16; kk++) {
            float hk = sb[kk];
            #pragma unroll
            for (int c = 0; c < IN_CH; c++) {
                hk += sWl[kk * IN_CH + c] * ag[c];
                hk += sWr[kk * IN_CH + c] * xa[c];
            }
            hk = fmaxf(hk, 0.0f);   // ReLU (dropout identity in eval)
            g0 += sWl2[kk] * hk;
            g1 += sWl2[HID_CH + kk] * hk;
            r0 += sWr2[kk] * hk;
            r1 += sWr2[HID_CH + kk] * hk;
        }
        g0 += __shfl_xor(g0, 1); g0 += __shfl_xor(g0, 2);
        g1 += __shfl_xor(g1, 1); g1 += __shfl_xor(g1, 2);
        r0 += __shfl_xor(r0, 1); r0 += __shfl_xor(r0, 2);
        r1 += __shfl_xor(r1, 1); r1 += __shfl_xor(r1, 2);
        if (l == 0) {
            g[(size_t)node * 2 + 0] = g0;
            g[(size_t)node * 2 + 1] = g1;
            float2 rt;
            rt.x = r0 + sb2[0];
            rt.y = r1 + sb2[1];
            *(float2*)(out_rt + (size_t)node * 2) = rt;
        }
    }
}

// Layer 2, one block per dst-range: same direct-accumulation structure.
// Per edge: 4B coalesced bucket read, 8B L2-hot gather of g[src], 2 ds_add_f32.
__global__ __launch_bounds__(512) void sage2_range(
        const int* __restrict__ bucket, const int* __restrict__ cursor,
        const int* __restrict__ deg, const float* __restrict__ g,
        float* __restrict__ out) {
    __shared__ float acc[RN * A2S];
    int tid = threadIdx.x;
    for (int i = tid; i < RN * A2S; i += 512) acc[i] = 0.0f;
    __syncthreads();

    int r = blockIdx.x;
    int len = cursor[r];
    if (len > CAP) len = CAP;
    const int* bin = bucket + (size_t)r * CAP;
    for (int j = tid; j < len; j += 512) {
        int w = bin[j];
        int s = w & 0x1FFFF;
        int dl = w >> 17;
        float2 gv = *(const float2*)(g + (size_t)s * 2);
        lds_fadd(&acc[dl * A2S + 0], gv.x);
        lds_fadd(&acc[dl * A2S + 1], gv.y);
    }
    __syncthreads();

    int node = r * RN + tid;
    if (tid < RN && node < N_NODES) {
        int dn = deg[node];
        float inv = 1.0f / fmaxf((float)dn, 1.0f);
        float2 rt = *(const float2*)(out + (size_t)node * 2);
        float2 ov;
        ov.x = acc[tid * A2S + 0] * inv + rt.x;
        ov.y = acc[tid * A2S + 1] * inv + rt.y;
        *(float2*)(out + (size_t)node * 2) = ov;
    }
}

extern "C" void kernel_launch(void* const* d_in, const int* in_sizes, int n_in,
                              void* d_out, int out_size, void* d_ws, size_t ws_size,
                              hipStream_t stream) {
    const float* x    = (const float*)d_in[0];
    const int*   ei   = (const int*)d_in[1];   // [2, N_EDGES] int32 per harness
    const float* W_l1 = (const float*)d_in[2];
    const float* b_l1 = (const float*)d_in[3];
    const float* W_r1 = (const float*)d_in[4];
    const float* W_l2 = (const float*)d_in[5];
    const float* b_l2 = (const float*)d_in[6];
    const float* W_r2 = (const float*)d_in[7];
    float* out = (float*)d_out;

    const int* src = ei;
    const int* dst = ei + N_EDGES;

    int*   cursor = (int*)d_ws;
    int*   bucket = (int*)d_ws + WS_BUCKET;
    int*   deg    = (int*)d_ws + WS_DEG;
    float* g      = (float*)d_ws + WS_G;

    hipMemsetAsync(cursor, 0, R2 * sizeof(int), stream);

    bucket_kernel<<<BB, 512, 0, stream>>>(src, dst, cursor, bucket);
    sage1_range<<<R2, 512, 0, stream>>>(bucket, cursor, x,
                                        W_l1, b_l1, W_r1, W_l2, b_l2, W_r2,
                                        deg, g, out);
    sage2_range<<<R2, 512, 0, stream>>>(bucket, cursor, deg, g, out);
}

// Round 3
// 152.249 us; speedup vs baseline: 1.3241x; 1.3241x over previous
//
#include <hip/hip_runtime.h>

#define N_NODES 100000
#define N_EDGES 1600000
#define IN_CH 8
#define HID_CH 64
#define OUT_CH 2

// 1024 dst-ranges of 98 nodes (1024*98 = 100352 >= 100000).
#define R2   1024
#define RN   98
#define CAP  1920    // per-range capacity; Binom mean 1568, sd ~40 -> +8.9 sigma
#define BB   256     // bucket blocks
#define BCHUNK (N_EDGES / BB)   // 6250 edges per bucket block

// cursor padded to one range per 64B cache line: 1024 ranges x 16 ints.
// Round-2 evidence: 262K returning global atomics on 1024 ints packed in 64
// lines -> 16 addresses/line serialized at the L2 atomic ALU (~85us bucket).
#define CSTRIDE 16

// Native LDS float atomic add (ds_add_f32, fire-and-forget).
__device__ __forceinline__ void lds_fadd(float* p, float v) {
    unsafeAtomicAdd(p, v);
}

// ---- workspace (4-byte words), ~10.2 MB ----
//   cursor : R2*CSTRIDE @ 0          (memset 0; per-range fill count, padded)
//   gbase  : BB*R2      @ WS_GBASE   (per-(block,range) reserved base)
//   bucket : R2*CAP     @ WS_BUCKET  (packed (dl<<17)|src; read by BOTH sage kernels)
//   deg    : R2*RN      @ WS_DEG     (in-degree per node)
//   g      : N*2 float  @ WS_G       (W_l2 @ h per node)
#define WS_GBASE  (R2 * CSTRIDE)
#define WS_BUCKET (WS_GBASE + BB * R2)
#define WS_DEG    (WS_BUCKET + R2 * CAP)
#define WS_G      (WS_DEG + R2 * RN)

// Phase 1: per-block histogram over dst-ranges, reserve slots via padded
// global atomics, record per-(block,range) base (coalesced 1MB write).
__global__ __launch_bounds__(512) void bucket_count(
        const int* __restrict__ dst, int* __restrict__ cursor,
        int* __restrict__ gbase) {
    __shared__ int cnt[R2];
    int tid = threadIdx.x;
    for (int i = tid; i < R2; i += 512) cnt[i] = 0;
    __syncthreads();
    const int* dch = dst + (size_t)blockIdx.x * BCHUNK;
    for (int j = tid; j < BCHUNK; j += 512)
        atomicAdd(&cnt[(unsigned)dch[j] / RN], 1);
    __syncthreads();
    int* gb = gbase + (size_t)blockIdx.x * R2;
    for (int i = tid; i < R2; i += 512) {
        int c = cnt[i];
        gb[i] = (c > 0) ? atomicAdd(&cursor[i * CSTRIDE], c) : 0;
    }
}

// Phase 2: re-read edges, place into reserved slots. LDS cursor starts at the
// reserved base; only LDS rtn atomics + scattered 4B bucket writes remain.
__global__ __launch_bounds__(512) void bucket_place(
        const int* __restrict__ src, const int* __restrict__ dst,
        const int* __restrict__ gbase, int* __restrict__ bucket) {
    __shared__ int cur[R2];
    int tid = threadIdx.x;
    const int* gb = gbase + (size_t)blockIdx.x * R2;
    for (int i = tid; i < R2; i += 512) cur[i] = gb[i];
    __syncthreads();
    const int* dch = dst + (size_t)blockIdx.x * BCHUNK;
    const int* sch = src + (size_t)blockIdx.x * BCHUNK;
    for (int j = tid; j < BCHUNK; j += 512) {
        unsigned d = (unsigned)dch[j];
        unsigned r = d / RN;
        unsigned dl = d - r * RN;
        int slot = atomicAdd(&cur[r], 1);
        if (slot < CAP)
            bucket[(size_t)r * CAP + slot] = (int)((dl << 17) | (unsigned)sch[j]);
    }
}

// Layer 1 (round-0 sorted structure, measured ~30us there): LDS counting-sort
// of the range's edges to node order (2 LDS atomics/edge + shfl scan), then
// 4-lane-per-node walk + distributed MLP. No CSR dump (sage2 reads the raw
// bucket directly); only deg[] goes to global.
__global__ __launch_bounds__(512) void sage1_range(
        const int* __restrict__ bucket, const int* __restrict__ cursor,
        const float* __restrict__ x,
        const float* __restrict__ W_l1, const float* __restrict__ b_l1,
        const float* __restrict__ W_r1,
        const float* __restrict__ W_l2, const float* __restrict__ b_l2,
        const float* __restrict__ W_r2,
        int* __restrict__ deg, float* __restrict__ g, float* __restrict__ out_rt) {
    __shared__ int raw[CAP];
    __shared__ int seg[CAP];
    __shared__ int scnt[128];
    __shared__ int soff[128];
    __shared__ int scur[128];
    __shared__ int wtot[2];
    __shared__ float sWl[HID_CH * IN_CH];
    __shared__ float sWr[HID_CH * IN_CH];
    __shared__ float sb[HID_CH];
    __shared__ float sWl2[OUT_CH * HID_CH];
    __shared__ float sWr2[OUT_CH * HID_CH];
    __shared__ float sb2[OUT_CH];

    int tid = threadIdx.x;
    for (int i = tid; i < HID_CH * IN_CH; i += 512) {
        sWl[i] = W_l1[i];
        sWr[i] = W_r1[i];
    }
    for (int i = tid; i < HID_CH; i += 512) sb[i] = b_l1[i];
    for (int i = tid; i < OUT_CH * HID_CH; i += 512) {
        sWl2[i] = W_l2[i];
        sWr2[i] = W_r2[i];
    }
    if (tid < OUT_CH) sb2[tid] = b_l2[tid];
    if (tid < 128) scnt[tid] = 0;

    int r = blockIdx.x;
    int len = cursor[r * CSTRIDE];
    if (len > CAP) len = CAP;
    const int* bin = bucket + (size_t)r * CAP;
    for (int j = tid; j < len; j += 512) raw[j] = bin[j];
    __syncthreads();

    for (int j = tid; j < len; j += 512) atomicAdd(&scnt[raw[j] >> 17], 1);
    __syncthreads();

    // Exclusive scan over 128 slots (RN=98 padded): per-wave shfl scan, 2 waves.
    int lane = tid & 63;
    if (tid < 128) {
        int v = scnt[tid];
        int incl = v;
        #pragma unroll
        for (int d = 1; d < 64; d <<= 1) {
            int t2 = __shfl_up(incl, d);
            if (lane >= d) incl += t2;
        }
        if (lane == 63) wtot[tid >> 6] = incl;
        soff[tid] = incl - v;
    }
    __syncthreads();
    if (tid < 128) {
        int o = soff[tid] + ((tid >= 64) ? wtot[0] : 0);
        soff[tid] = o;
        scur[tid] = o;
    }
    __syncthreads();

    for (int j = tid; j < len; j += 512) {
        int w = raw[j];
        int p = atomicAdd(&scur[w >> 17], 1);
        seg[p] = w & 0x1FFFF;
    }
    __syncthreads();

    // Walk: 4 lanes per node, independent (pipelineable) LDS + global loads.
    int q = tid >> 2;
    int l = tid & 3;
    int node = r * RN + q;
    if (q < RN && node < N_NODES) {
        int o = soff[q];
        int dn = scnt[q];
        if (l == 0) deg[node] = dn;

        float acc[IN_CH];
        #pragma unroll
        for (int c = 0; c < IN_CH; c++) acc[c] = 0.0f;
        for (int j = o + l; j < o + dn; j += 4) {
            int s = seg[j];
            const float4* xs = (const float4*)(x + (size_t)s * IN_CH);
            float4 a = xs[0];
            float4 b = xs[1];
            acc[0] += a.x; acc[1] += a.y; acc[2] += a.z; acc[3] += a.w;
            acc[4] += b.x; acc[5] += b.y; acc[6] += b.z; acc[7] += b.w;
        }
        #pragma unroll
        for (int c = 0; c < IN_CH; c++) {
            acc[c] += __shfl_xor(acc[c], 1);
            acc[c] += __shfl_xor(acc[c], 2);
        }
        float inv = 1.0f / fmaxf((float)dn, 1.0f);
        float ag[IN_CH], xa[IN_CH];
        #pragma unroll
        for (int c = 0; c < IN_CH; c++) ag[c] = acc[c] * inv;
        const float4* xp = (const float4*)(x + (size_t)node * IN_CH);
        float4 x0 = xp[0], x1 = xp[1];
        xa[0] = x0.x; xa[1] = x0.y; xa[2] = x0.z; xa[3] = x0.w;
        xa[4] = x1.x; xa[5] = x1.y; xa[6] = x1.z; xa[7] = x1.w;

        // Distributed MLP: lane l handles hidden units [16l, 16l+16).
        float g0 = 0.f, g1 = 0.f, r0 = 0.f, r1 = 0.f;
        int k0 = l * 16;
        #pragma unroll 4
        for (int kk = k0; kk < k0 + 16; kk++) {
            float hk = sb[kk];
            #pragma unroll
            for (int c = 0; c < IN_CH; c++) {
                hk += sWl[kk * IN_CH + c] * ag[c];
                hk += sWr[kk * IN_CH + c] * xa[c];
            }
            hk = fmaxf(hk, 0.0f);   // ReLU (dropout identity in eval)
            g0 += sWl2[kk] * hk;
            g1 += sWl2[HID_CH + kk] * hk;
            r0 += sWr2[kk] * hk;
            r1 += sWr2[HID_CH + kk] * hk;
        }
        g0 += __shfl_xor(g0, 1); g0 += __shfl_xor(g0, 2);
        g1 += __shfl_xor(g1, 1); g1 += __shfl_xor(g1, 2);
        r0 += __shfl_xor(r0, 1); r0 += __shfl_xor(r0, 2);
        r1 += __shfl_xor(r1, 1); r1 += __shfl_xor(r1, 2);
        if (l == 0) {
            g[(size_t)node * 2 + 0] = g0;
            g[(size_t)node * 2 + 1] = g1;
            float2 rt;
            rt.x = r0 + sb2[0];
            rt.y = r1 + sb2[1];
            *(float2*)(out_rt + (size_t)node * 2) = rt;
        }
    }
}

// Layer 2: direct LDS accumulation straight from the unsorted bucket.
// Per edge: 4B coalesced bucket read, 8B L2-hot gather of g[src], 2 ds_add_f32.
__global__ __launch_bounds__(512) void sage2_range(
        const int* __restrict__ bucket, const int* __restrict__ cursor,
        const int* __restrict__ deg, const float* __restrict__ g,
        float* __restrict__ out) {
    __shared__ float acc[RN * 3];
    int tid = threadIdx.x;
    for (int i = tid; i < RN * 3; i += 512) acc[i] = 0.0f;
    __syncthreads();

    int r = blockIdx.x;
    int len = cursor[r * CSTRIDE];
    if (len > CAP) len = CAP;
    const int* bin = bucket + (size_t)r * CAP;
    for (int j = tid; j < len; j += 512) {
        int w = bin[j];
        int s = w & 0x1FFFF;
        int dl = w >> 17;
        float2 gv = *(const float2*)(g + (size_t)s * 2);
        lds_fadd(&acc[dl * 3 + 0], gv.x);
        lds_fadd(&acc[dl * 3 + 1], gv.y);
    }
    __syncthreads();

    int node = r * RN + tid;
    if (tid < RN && node < N_NODES) {
        int dn = deg[node];
        float inv = 1.0f / fmaxf((float)dn, 1.0f);
        float2 rt = *(const float2*)(out + (size_t)node * 2);
        float2 ov;
        ov.x = acc[tid * 3 + 0] * inv + rt.x;
        ov.y = acc[tid * 3 + 1] * inv + rt.y;
        *(float2*)(out + (size_t)node * 2) = ov;
    }
}

extern "C" void kernel_launch(void* const* d_in, const int* in_sizes, int n_in,
                              void* d_out, int out_size, void* d_ws, size_t ws_size,
                              hipStream_t stream) {
    const float* x    = (const float*)d_in[0];
    const int*   ei   = (const int*)d_in[1];   // [2, N_EDGES] int32 per harness
    const float* W_l1 = (const float*)d_in[2];
    const float* b_l1 = (const float*)d_in[3];
    const float* W_r1 = (const float*)d_in[4];
    const float* W_l2 = (const float*)d_in[5];
    const float* b_l2 = (const float*)d_in[6];
    const float* W_r2 = (const float*)d_in[7];
    float* out = (float*)d_out;

    const int* src = ei;
    const int* dst = ei + N_EDGES;

    int*   cursor = (int*)d_ws;
    int*   gbase  = (int*)d_ws + WS_GBASE;
    int*   bucket = (int*)d_ws + WS_BUCKET;
    int*   deg    = (int*)d_ws + WS_DEG;
    float* g      = (float*)d_ws + WS_G;

    hipMemsetAsync(cursor, 0, R2 * CSTRIDE * sizeof(int), stream);

    bucket_count<<<BB, 512, 0, stream>>>(dst, cursor, gbase);
    bucket_place<<<BB, 512, 0, stream>>>(src, dst, gbase, bucket);
    sage1_range<<<R2, 512, 0, stream>>>(bucket, cursor, x,
                                        W_l1, b_l1, W_r1, W_l2, b_l2, W_r2,
                                        deg, g, out);
    sage2_range<<<R2, 512, 0, stream>>>(bucket, cursor, deg, g, out);
}

// Round 4
// 147.043 us; speedup vs baseline: 1.3710x; 1.0354x over previous
//
#include <hip/hip_runtime.h>

#define N_NODES 100000
#define N_EDGES 1600000
#define IN_CH 8
#define HID_CH 64
#define OUT_CH 2

// 1024 dst-ranges of 98 nodes (1024*98 = 100352 >= 100000).
#define R2   1024
#define RN   98
#define CAP  1920    // per-range capacity; Binom mean 1568, sd ~40 -> +8.9 sigma
#define BB   256     // bucket blocks
#define BT   1024    // bucket threads: 1 block/CU -> 16 waves/CU (4/SIMD)
#define BCHUNK (N_EDGES / BB)   // 6250 edges per bucket block (3125 int2, 8B-aligned)

// cursor padded to one range per 64B cache line (round-3: kept).
#define CSTRIDE 16

// Native LDS float atomic add (ds_add_f32, fire-and-forget).
__device__ __forceinline__ void lds_fadd(float* p, float v) {
    unsafeAtomicAdd(p, v);
}

// ---- workspace (4-byte words), ~10.2 MB ----
//   cursor : R2*CSTRIDE @ 0          (memset 0; per-range fill count, padded)
//   gbase  : BB*R2      @ WS_GBASE   (per-(block,range) reserved base)
//   bucket : R2*CAP     @ WS_BUCKET  (packed (dl<<17)|src; read by BOTH sage kernels)
//   deg    : R2*RN      @ WS_DEG     (in-degree per node)
//   g      : N*2 float  @ WS_G       (W_l2 @ h per node)
#define WS_GBASE  (R2 * CSTRIDE)
#define WS_BUCKET (WS_GBASE + BB * R2)
#define WS_DEG    (WS_BUCKET + R2 * CAP)
#define WS_G      (WS_DEG + R2 * RN)

// Phase 1: per-block LDS histogram over dst-ranges, reserve via padded global
// atomics. Round-4 change: 1024 threads (was 512; 2 waves/SIMD starved latency
// hiding) + int2 edge reads (2 independent chains/iter, 4 outer iters).
__global__ __launch_bounds__(BT) void bucket_count(
        const int* __restrict__ dst, int* __restrict__ cursor,
        int* __restrict__ gbase) {
    __shared__ int cnt[R2];
    int tid = threadIdx.x;
    if (tid < R2) cnt[tid] = 0;
    __syncthreads();
    const int2* dch2 = (const int2*)(dst + (size_t)blockIdx.x * BCHUNK);
    for (int i = tid; i < BCHUNK / 2; i += BT) {
        int2 d = dch2[i];
        atomicAdd(&cnt[(unsigned)d.x / RN], 1);
        atomicAdd(&cnt[(unsigned)d.y / RN], 1);
    }
    __syncthreads();
    int* gb = gbase + (size_t)blockIdx.x * R2;
    if (tid < R2) {
        int c = cnt[tid];
        gb[tid] = (c > 0) ? atomicAdd(&cursor[tid * CSTRIDE], c) : 0;
    }
}

// Phase 2: re-read edges, place into reserved slots (LDS rtn atomics +
// scattered 4B bucket writes). Same occupancy/ILP treatment.
__global__ __launch_bounds__(BT) void bucket_place(
        const int* __restrict__ src, const int* __restrict__ dst,
        const int* __restrict__ gbase, int* __restrict__ bucket) {
    __shared__ int cur[R2];
    int tid = threadIdx.x;
    const int* gb = gbase + (size_t)blockIdx.x * R2;
    if (tid < R2) cur[tid] = gb[tid];
    __syncthreads();
    const int2* dch2 = (const int2*)(dst + (size_t)blockIdx.x * BCHUNK);
    const int2* sch2 = (const int2*)(src + (size_t)blockIdx.x * BCHUNK);
    for (int i = tid; i < BCHUNK / 2; i += BT) {
        int2 d = dch2[i];
        int2 s = sch2[i];
        {
            unsigned dd = (unsigned)d.x;
            unsigned r = dd / RN;
            unsigned dl = dd - r * RN;
            int slot = atomicAdd(&cur[r], 1);
            if (slot < CAP)
                bucket[(size_t)r * CAP + slot] = (int)((dl << 17) | (unsigned)s.x);
        }
        {
            unsigned dd = (unsigned)d.y;
            unsigned r = dd / RN;
            unsigned dl = dd - r * RN;
            int slot = atomicAdd(&cur[r], 1);
            if (slot < CAP)
                bucket[(size_t)r * CAP + slot] = (int)((dl << 17) | (unsigned)s.y);
        }
    }
}

// Layer 1 (round-0 sorted structure): LDS counting-sort of the range's edges
// to node order (2 LDS atomics/edge + shfl scan), then 4-lane-per-node walk +
// distributed MLP. No CSR dump; only deg[] goes to global.
__global__ __launch_bounds__(512) void sage1_range(
        const int* __restrict__ bucket, const int* __restrict__ cursor,
        const float* __restrict__ x,
        const float* __restrict__ W_l1, const float* __restrict__ b_l1,
        const float* __restrict__ W_r1,
        const float* __restrict__ W_l2, const float* __restrict__ b_l2,
        const float* __restrict__ W_r2,
        int* __restrict__ deg, float* __restrict__ g, float* __restrict__ out_rt) {
    __shared__ int raw[CAP];
    __shared__ int seg[CAP];
    __shared__ int scnt[128];
    __shared__ int soff[128];
    __shared__ int scur[128];
    __shared__ int wtot[2];
    __shared__ float sWl[HID_CH * IN_CH];
    __shared__ float sWr[HID_CH * IN_CH];
    __shared__ float sb[HID_CH];
    __shared__ float sWl2[OUT_CH * HID_CH];
    __shared__ float sWr2[OUT_CH * HID_CH];
    __shared__ float sb2[OUT_CH];

    int tid = threadIdx.x;
    for (int i = tid; i < HID_CH * IN_CH; i += 512) {
        sWl[i] = W_l1[i];
        sWr[i] = W_r1[i];
    }
    for (int i = tid; i < HID_CH; i += 512) sb[i] = b_l1[i];
    for (int i = tid; i < OUT_CH * HID_CH; i += 512) {
        sWl2[i] = W_l2[i];
        sWr2[i] = W_r2[i];
    }
    if (tid < OUT_CH) sb2[tid] = b_l2[tid];
    if (tid < 128) scnt[tid] = 0;

    int r = blockIdx.x;
    int len = cursor[r * CSTRIDE];
    if (len > CAP) len = CAP;
    const int* bin = bucket + (size_t)r * CAP;
    for (int j = tid; j < len; j += 512) raw[j] = bin[j];
    __syncthreads();

    for (int j = tid; j < len; j += 512) atomicAdd(&scnt[raw[j] >> 17], 1);
    __syncthreads();

    // Exclusive scan over 128 slots (RN=98 padded): per-wave shfl scan, 2 waves.
    int lane = tid & 63;
    if (tid < 128) {
        int v = scnt[tid];
        int incl = v;
        #pragma unroll
        for (int d = 1; d < 64; d <<= 1) {
            int t2 = __shfl_up(incl, d);
            if (lane >= d) incl += t2;
        }
        if (lane == 63) wtot[tid >> 6] = incl;
        soff[tid] = incl - v;
    }
    __syncthreads();
    if (tid < 128) {
        int o = soff[tid] + ((tid >= 64) ? wtot[0] : 0);
        soff[tid] = o;
        scur[tid] = o;
    }
    __syncthreads();

    for (int j = tid; j < len; j += 512) {
        int w = raw[j];
        int p = atomicAdd(&scur[w >> 17], 1);
        seg[p] = w & 0x1FFFF;
    }
    __syncthreads();

    // Walk: 4 lanes per node, independent (pipelineable) LDS + global loads.
    int q = tid >> 2;
    int l = tid & 3;
    int node = r * RN + q;
    if (q < RN && node < N_NODES) {
        int o = soff[q];
        int dn = scnt[q];
        if (l == 0) deg[node] = dn;

        float acc[IN_CH];
        #pragma unroll
        for (int c = 0; c < IN_CH; c++) acc[c] = 0.0f;
        for (int j = o + l; j < o + dn; j += 4) {
            int s = seg[j];
            const float4* xs = (const float4*)(x + (size_t)s * IN_CH);
            float4 a = xs[0];
            float4 b = xs[1];
            acc[0] += a.x; acc[1] += a.y; acc[2] += a.z; acc[3] += a.w;
            acc[4] += b.x; acc[5] += b.y; acc[6] += b.z; acc[7] += b.w;
        }
        #pragma unroll
        for (int c = 0; c < IN_CH; c++) {
            acc[c] += __shfl_xor(acc[c], 1);
            acc[c] += __shfl_xor(acc[c], 2);
        }
        float inv = 1.0f / fmaxf((float)dn, 1.0f);
        float ag[IN_CH], xa[IN_CH];
        #pragma unroll
        for (int c = 0; c < IN_CH; c++) ag[c] = acc[c] * inv;
        const float4* xp = (const float4*)(x + (size_t)node * IN_CH);
        float4 x0 = xp[0], x1 = xp[1];
        xa[0] = x0.x; xa[1] = x0.y; xa[2] = x0.z; xa[3] = x0.w;
        xa[4] = x1.x; xa[5] = x1.y; xa[6] = x1.z; xa[7] = x1.w;

        // Distributed MLP: lane l handles hidden units [16l, 16l+16).
        float g0 = 0.f, g1 = 0.f, r0 = 0.f, r1 = 0.f;
        int k0 = l * 16;
        #pragma unroll 4
        for (int kk = k0; kk < k0 + 16; kk++) {
            float hk = sb[kk];
            #pragma unroll
            for (int c = 0; c < IN_CH; c++) {
                hk += sWl[kk * IN_CH + c] * ag[c];
                hk += sWr[kk * IN_CH + c] * xa[c];
            }
            hk = fmaxf(hk, 0.0f);   // ReLU (dropout identity in eval)
            g0 += sWl2[kk] * hk;
            g1 += sWl2[HID_CH + kk] * hk;
            r0 += sWr2[kk] * hk;
            r1 += sWr2[HID_CH + kk] * hk;
        }
        g0 += __shfl_xor(g0, 1); g0 += __shfl_xor(g0, 2);
        g1 += __shfl_xor(g1, 1); g1 += __shfl_xor(g1, 2);
        r0 += __shfl_xor(r0, 1); r0 += __shfl_xor(r0, 2);
        r1 += __shfl_xor(r1, 1); r1 += __shfl_xor(r1, 2);
        if (l == 0) {
            g[(size_t)node * 2 + 0] = g0;
            g[(size_t)node * 2 + 1] = g1;
            float2 rt;
            rt.x = r0 + sb2[0];
            rt.y = r1 + sb2[1];
            *(float2*)(out_rt + (size_t)node * 2) = rt;
        }
    }
}

// Layer 2: direct LDS accumulation straight from the unsorted bucket.
// Per edge: 4B coalesced bucket read, 8B L2-hot gather of g[src], 2 ds_add_f32.
__global__ __launch_bounds__(512) void sage2_range(
        const int* __restrict__ bucket, const int* __restrict__ cursor,
        const int* __restrict__ deg, const float* __restrict__ g,
        float* __restrict__ out) {
    __shared__ float acc[RN * 3];
    int tid = threadIdx.x;
    for (int i = tid; i < RN * 3; i += 512) acc[i] = 0.0f;
    __syncthreads();

    int r = blockIdx.x;
    int len = cursor[r * CSTRIDE];
    if (len > CAP) len = CAP;
    const int* bin = bucket + (size_t)r * CAP;
    for (int j = tid; j < len; j += 512) {
        int w = bin[j];
        int s = w & 0x1FFFF;
        int dl = w >> 17;
        float2 gv = *(const float2*)(g + (size_t)s * 2);
        lds_fadd(&acc[dl * 3 + 0], gv.x);
        lds_fadd(&acc[dl * 3 + 1], gv.y);
    }
    __syncthreads();

    int node = r * RN + tid;
    if (tid < RN && node < N_NODES) {
        int dn = deg[node];
        float inv = 1.0f / fmaxf((float)dn, 1.0f);
        float2 rt = *(const float2*)(out + (size_t)node * 2);
        float2 ov;
        ov.x = acc[tid * 3 + 0] * inv + rt.x;
        ov.y = acc[tid * 3 + 1] * inv + rt.y;
        *(float2*)(out + (size_t)node * 2) = ov;
    }
}

extern "C" void kernel_launch(void* const* d_in, const int* in_sizes, int n_in,
                              void* d_out, int out_size, void* d_ws, size_t ws_size,
                              hipStream_t stream) {
    const float* x    = (const float*)d_in[0];
    const int*   ei   = (const int*)d_in[1];   // [2, N_EDGES] int32 per harness
    const float* W_l1 = (const float*)d_in[2];
    const float* b_l1 = (const float*)d_in[3];
    const float* W_r1 = (const float*)d_in[4];
    const float* W_l2 = (const float*)d_in[5];
    const float* b_l2 = (const float*)d_in[6];
    const float* W_r2 = (const float*)d_in[7];
    float* out = (float*)d_out;

    const int* src = ei;
    const int* dst = ei + N_EDGES;

    int*   cursor = (int*)d_ws;
    int*   gbase  = (int*)d_ws + WS_GBASE;
    int*   bucket = (int*)d_ws + WS_BUCKET;
    int*   deg    = (int*)d_ws + WS_DEG;
    float* g      = (float*)d_ws + WS_G;

    hipMemsetAsync(cursor, 0, R2 * CSTRIDE * sizeof(int), stream);

    bucket_count<<<BB, BT, 0, stream>>>(dst, cursor, gbase);
    bucket_place<<<BB, BT, 0, stream>>>(src, dst, gbase, bucket);
    sage1_range<<<R2, 512, 0, stream>>>(bucket, cursor, x,
                                        W_l1, b_l1, W_r1, W_l2, b_l2, W_r2,
                                        deg, g, out);
    sage2_range<<<R2, 512, 0, stream>>>(bucket, cursor, deg, g, out);
}